// Round 18
// baseline (45.326 us; speedup 1.0000x reference)
//
#include <hip/hip_runtime.h>
#include <float.h>
#include <math.h>

#define B_   4
#define S_   2048
#define DIN_ 256
#define DH_  128
#define NB_  50
#define ROWS (B_ * S_)

#define SETUP_BLOCKS 14                     // 14 x 512 = 7168 slots
#define PLDDT_ROWSPB 32
#define PLDDT_BLOCKS (ROWS / PLDDT_ROWSPB)  // 256
#define MB_ROWS      128                    // rows per MLP block (8 waves x 16)
#define MLP_BLOCKS   (ROWS / MB_ROWS)       // 64

typedef __attribute__((ext_vector_type(8))) short  short8;
typedef __attribute__((ext_vector_type(4))) float  f32x4;
typedef __attribute__((ext_vector_type(2))) float  f32x2;

__device__ __forceinline__ unsigned short bf16_rne(float f) {
    unsigned u = __builtin_bit_cast(unsigned, f);
    u = u + 0x7fffu + ((u >> 16) & 1u);
    return (unsigned short)(u >> 16);
}

// ---------------------------------------------------------------------------
// Kernel A (R13-verified, verbatim): blocks [0,14) = weight setup;
// [14, 14+256) = pLDDT, 32 rows/block. pLDDT never reads wt.
// ---------------------------------------------------------------------------
__global__ __launch_bounds__(512) void kernelA(
    const float* __restrict__ W1, const float* __restrict__ W2,
    const float* __restrict__ W3, unsigned short* __restrict__ wt,
    const float* __restrict__ coords, const float* __restrict__ mask,
    float* __restrict__ out_plddt)
{
    __shared__ f32x4 sP[S_];
    const int tid = threadIdx.x;

    if (blockIdx.x < SETUP_BLOCKS) {
        const int t = blockIdx.x * 512 + tid;           // 0..7167
        const int l = t & 63, m = l & 15, kg = l >> 4;
        float src[8];
        int dst;
        if (t < 4096) {
            const int c = t >> 6, nt = c >> 3, ks = c & 7;
            const int n = nt * 16 + m, k = ks * 32 + kg * 8;
#pragma unroll
            for (int i = 0; i < 8; ++i) src[i] = W1[(k + i) * DH_ + n];
            dst = t * 8;
        } else if (t < 6144) {
            const int s = t - 4096, c = s >> 6, nt = c >> 2, ks = c & 3;
            const int n = nt * 16 + m, k = ks * 32 + kg * 8;
#pragma unroll
            for (int i = 0; i < 8; ++i) src[i] = W2[(k + i) * DH_ + n];
            dst = 32768 + s * 8;
        } else {
            const int s = t - 6144, c = s >> 6, nt = c >> 2, ks = c & 3;
            const int n = nt * 16 + m, k = ks * 32 + kg * 8;
#pragma unroll
            for (int i = 0; i < 8; ++i) src[i] = (n < NB_) ? W3[(k + i) * NB_ + n] : 0.f;
            dst = 49152 + s * 8;
        }
        union { short8 v; unsigned short u[8]; } H;
#pragma unroll
        for (int i = 0; i < 8; ++i) H.u[i] = bf16_rne(src[i]);
        *(short8*)&wt[dst] = H.v;
        return;
    }

    // ==================== pLDDT path (32 rows/block) ====================
    const int lane = tid & 63;
    const int w    = tid >> 6;
    const int pb   = blockIdx.x - SETUP_BLOCKS;      // 0..255
    const int row0 = pb * PLDDT_ROWSPB;
    const int b    = row0 >> 11;
    const int ib0  = row0 & (S_ - 1);

    const float* cb = coords + (size_t)b * S_ * 3;
    const float* mb = mask   + (size_t)b * S_;

    {
        union { f32x4 v[3]; float f[12]; } C;
        const float* cp = cb + tid * 12;
#pragma unroll
        for (int q = 0; q < 3; ++q) C.v[q] = *(const f32x4*)(cp + q * 4);
        union { f32x4 v; float f[4]; } M;
        M.v = *(const f32x4*)(mb + tid * 4);
#pragma unroll
        for (int q = 0; q < 4; ++q)
            sP[tid * 4 + q] = (f32x4){C.f[q*3], C.f[q*3+1], C.f[q*3+2], M.f[q]};
    }
    __syncthreads();

    f32x4 PI[4];
#pragma unroll
    for (int ii = 0; ii < 4; ++ii) PI[ii] = sP[ib0 + w * 4 + ii];

    const f32x2 Px[2] = {{PI[0][0], PI[1][0]}, {PI[2][0], PI[3][0]}};
    const f32x2 Py[2] = {{PI[0][1], PI[1][1]}, {PI[2][1], PI[3][1]}};
    const f32x2 Pz[2] = {{PI[0][2], PI[1][2]}, {PI[2][2], PI[3][2]}};

    int cnt[4] = {0,0,0,0}, ws[4] = {0,0,0,0};
#pragma unroll 2
    for (int j = lane; j < S_; j += 64) {
        const f32x4 p = sP[j];
        const float gd = (p[3] > 0.f) ? 1e-35f : 1e30f;
        const f32x2 pg = {gd, gd};
        const f32x2 px = {p[0], p[0]}, py = {p[1], p[1]}, pz = {p[2], p[2]};
#pragma unroll
        for (int pr = 0; pr < 2; ++pr) {
            f32x2 dx = Px[pr] - px;
            f32x2 dy = Py[pr] - py;
            f32x2 dz = Pz[pr] - pz;
            f32x2 d2 = __builtin_elementwise_fma(dx, dx,
                       __builtin_elementwise_fma(dy, dy,
                       __builtin_elementwise_fma(dz, dz, pg)));
#pragma unroll
            for (int el = 0; el < 2; ++el) {
                const int ii = pr * 2 + el;
                const float d2e = d2[el];
                cnt[ii] += (d2e <= 225.f);
                const unsigned u = __builtin_bit_cast(unsigned, d2e);
                int c = (132 - (int)((u - 1u) >> 23)) >> 1;
                c = c < 0 ? 0 : (c > 4 ? 4 : c);
                ws[ii] += c;
            }
        }
    }
#pragma unroll
    for (int ii = 0; ii < 4; ++ii) {
        int acc = (cnt[ii] << 16) | ws[ii];
        for (int off = 32; off; off >>= 1) acc += __shfl_xor(acc, off);
        if (lane == 0) {
            const int ct = acc >> 16, wv = acc & 0xFFFF;
            const float r = (ct > 0) ? (wv * 25.f / (float)ct) : 0.f;
            out_plddt[row0 + w * 4 + ii] = r * PI[ii][3];
        }
    }
}

// ---------------------------------------------------------------------------
// Kernel B: in-wave MLP (R9-verified math). 8 waves x 16 rows = 128 rows/blk,
// 64 blocks. ONE barrier; each wave end-to-end independent.
// __launch_bounds__(512, 2): VGPR budget 256 -> no spill (R9's failure mode).
// ---------------------------------------------------------------------------
__global__ __launch_bounds__(512, 2) void mlp_inwave(
    const float* __restrict__ x, const float* __restrict__ mask,
    const float* __restrict__ b1, const float* __restrict__ g1, const float* __restrict__ be1,
    const float* __restrict__ b2, const float* __restrict__ g2, const float* __restrict__ be2,
    const float* __restrict__ b3, const float* __restrict__ temp,
    const unsigned short* __restrict__ wt,
    float* __restrict__ out_logits, float* __restrict__ out_probs)
{
    __shared__ unsigned short sX[MB_ROWS * DIN_];   // 64 KB
    const int tid  = threadIdx.x;
    const int lane = tid & 63;
    const int w    = tid >> 6;          // wave 0..7
    const int m    = lane & 15;
    const int kg   = lane >> 4;
    const int row0 = blockIdx.x * MB_ROWS;

    // ---- stage x[128][256] -> swizzled bf16 (coalesced, ONE barrier) ----
#pragma unroll
    for (int q = 0; q < 8; ++q) {
        const int idx = q * 4096 + tid * 8;           // f32 index in tile
        const float* xp = x + (size_t)row0 * DIN_ + idx;
        f32x4 va = *(const f32x4*)xp;
        f32x4 vb = *(const f32x4*)(xp + 4);
        union { short8 v; unsigned short u[8]; } H;
#pragma unroll
        for (int i = 0; i < 8; ++i)
            H.u[i] = bf16_rne((i < 4) ? va[i] : vb[i - 4]);
        const int r = idx >> 8, c = idx & 255;
        *(short8*)&sX[(r * 256 + c) ^ ((r & 7) << 3)] = H.v;
    }
    __syncthreads();

    const int wb = w * 4096;   // wave-private u16 base (16 rows x 256)

    // ---- stage 1: [16x256] @ [256x128], all in-wave ----
    short8 a1[8];
#pragma unroll
    for (int ks = 0; ks < 8; ++ks)
        a1[ks] = *(const short8*)&sX[wb + ((m * 256 + ks * 32 + kg * 8) ^ ((m & 7) << 3))];
    f32x4 acc[8];
#pragma unroll
    for (int nt = 0; nt < 8; ++nt) acc[nt] = (f32x4){0.f, 0.f, 0.f, 0.f};
#pragma unroll
    for (int nt = 0; nt < 8; ++nt)
#pragma unroll
        for (int ks = 0; ks < 8; ++ks) {
            short8 bh = *(const short8*)&wt[(nt * 8 + ks) * 512 + lane * 8];
            acc[nt] = __builtin_amdgcn_mfma_f32_16x16x32_bf16(a1[ks], bh, acc[nt], 0, 0, 0);
        }

    // ---- LN1 + relu (in-wave: in-lane nt-sum + shfl over 16 m-lanes) ----
    {
        float v[8][4], Sj[4] = {0,0,0,0}, Qj[4] = {0,0,0,0};
#pragma unroll
        for (int nt = 0; nt < 8; ++nt) {
            const float bv = b1[nt * 16 + m];
#pragma unroll
            for (int j = 0; j < 4; ++j) {
                const float t = acc[nt][j] + bv;
                v[nt][j] = t; Sj[j] += t; Qj[j] += t * t;
            }
        }
#pragma unroll
        for (int j = 0; j < 4; ++j)
            for (int off = 1; off < 16; off <<= 1) {
                Sj[j] += __shfl_xor(Sj[j], off);
                Qj[j] += __shfl_xor(Qj[j], off);
            }
        float mean[4], inv[4];
#pragma unroll
        for (int j = 0; j < 4; ++j) {
            mean[j] = Sj[j] * (1.f / DH_);
            inv[j]  = rsqrtf(Qj[j] * (1.f / DH_) - mean[j] * mean[j] + 1e-5f);
        }
#pragma unroll
        for (int nt = 0; nt < 8; ++nt) {
            const float gv = g1[nt * 16 + m], ev = be1[nt * 16 + m];
#pragma unroll
            for (int j = 0; j < 4; ++j) {
                const float h = fmaxf(fmaf((v[nt][j] - mean[j]) * inv[j], gv, ev), 0.f);
                const int r = kg * 4 + j;
                sX[wb + ((r * 128 + nt * 16 + m) ^ ((r & 7) << 3))] = bf16_rne(h);
            }
        }
    }

    // ---- stage 2: [16x128] @ [128x128] ----
    short8 a2[4];
#pragma unroll
    for (int ks = 0; ks < 4; ++ks)
        a2[ks] = *(const short8*)&sX[wb + ((m * 128 + ks * 32 + kg * 8) ^ ((m & 7) << 3))];
    f32x4 acc2[8];
#pragma unroll
    for (int nt = 0; nt < 8; ++nt) acc2[nt] = (f32x4){0.f, 0.f, 0.f, 0.f};
#pragma unroll
    for (int nt = 0; nt < 8; ++nt)
#pragma unroll
        for (int ks = 0; ks < 4; ++ks) {
            short8 bh = *(const short8*)&wt[32768 + (nt * 4 + ks) * 512 + lane * 8];
            acc2[nt] = __builtin_amdgcn_mfma_f32_16x16x32_bf16(a2[ks], bh, acc2[nt], 0, 0, 0);
        }

    // ---- LN2 + relu ----
    {
        float v[8][4], Sj[4] = {0,0,0,0}, Qj[4] = {0,0,0,0};
#pragma unroll
        for (int nt = 0; nt < 8; ++nt) {
            const float bv = b2[nt * 16 + m];
#pragma unroll
            for (int j = 0; j < 4; ++j) {
                const float t = acc2[nt][j] + bv;
                v[nt][j] = t; Sj[j] += t; Qj[j] += t * t;
            }
        }
#pragma unroll
        for (int j = 0; j < 4; ++j)
            for (int off = 1; off < 16; off <<= 1) {
                Sj[j] += __shfl_xor(Sj[j], off);
                Qj[j] += __shfl_xor(Qj[j], off);
            }
        float mean[4], inv[4];
#pragma unroll
        for (int j = 0; j < 4; ++j) {
            mean[j] = Sj[j] * (1.f / DH_);
            inv[j]  = rsqrtf(Qj[j] * (1.f / DH_) - mean[j] * mean[j] + 1e-5f);
        }
#pragma unroll
        for (int nt = 0; nt < 8; ++nt) {
            const float gv = g2[nt * 16 + m], ev = be2[nt * 16 + m];
#pragma unroll
            for (int j = 0; j < 4; ++j) {
                const float h = fmaxf(fmaf((v[nt][j] - mean[j]) * inv[j], gv, ev), 0.f);
                const int r = kg * 4 + j;
                sX[wb + ((r * 128 + nt * 16 + m) ^ ((r & 7) << 3))] = bf16_rne(h);
            }
        }
    }

    // ---- stage 3: [16x128] @ [128x64pad] + softmax + stores, in-wave ----
    {
        short8 a3[4];
#pragma unroll
        for (int ks = 0; ks < 4; ++ks)
            a3[ks] = *(const short8*)&sX[wb + ((m * 128 + ks * 32 + kg * 8) ^ ((m & 7) << 3))];
        f32x4 acc3[4];
#pragma unroll
        for (int nt = 0; nt < 4; ++nt) acc3[nt] = (f32x4){0.f, 0.f, 0.f, 0.f};
#pragma unroll
        for (int nt = 0; nt < 4; ++nt)
#pragma unroll
            for (int ks = 0; ks < 4; ++ks) {
                short8 bh = *(const short8*)&wt[49152 + (nt * 4 + ks) * 512 + lane * 8];
                acc3[nt] = __builtin_amdgcn_mfma_f32_16x16x32_bf16(a3[ks], bh, acc3[nt], 0, 0, 0);
            }
        const float invT = 1.f / temp[0];
        float lv[4][4], ev[4][4], mx[4], sm[4];
#pragma unroll
        for (int j = 0; j < 4; ++j) { mx[j] = -FLT_MAX; sm[j] = 0.f; }
#pragma unroll
        for (int nt = 0; nt < 4; ++nt) {
            const int col = nt * 16 + m;
            const float bv = (col < NB_) ? b3[col] : 0.f;
#pragma unroll
            for (int j = 0; j < 4; ++j) {
                const float t = (acc3[nt][j] + bv) * invT;
                lv[nt][j] = t;
                if (col < NB_) mx[j] = fmaxf(mx[j], t);
            }
        }
#pragma unroll
        for (int j = 0; j < 4; ++j)
            for (int off = 1; off < 16; off <<= 1)
                mx[j] = fmaxf(mx[j], __shfl_xor(mx[j], off));
#pragma unroll
        for (int nt = 0; nt < 4; ++nt) {
            const int col = nt * 16 + m;
#pragma unroll
            for (int j = 0; j < 4; ++j) {
                const float e = (col < NB_) ? expf(lv[nt][j] - mx[j]) : 0.f;
                ev[nt][j] = e; sm[j] += e;
            }
        }
#pragma unroll
        for (int j = 0; j < 4; ++j)
            for (int off = 1; off < 16; off <<= 1)
                sm[j] += __shfl_xor(sm[j], off);
#pragma unroll
        for (int j = 0; j < 4; ++j) {
            const float isum = 1.f / sm[j];
            const int ra = row0 + w * 16 + kg * 4 + j;
            const float mk = mask[ra];
            float* ol = out_logits + (size_t)ra * NB_;
            float* op = out_probs  + (size_t)ra * NB_;
#pragma unroll
            for (int nt = 0; nt < 4; ++nt) {
                const int col = nt * 16 + m;
                if (col < NB_) {
                    ol[col] = lv[nt][j] * mk;
                    op[col] = ev[nt][j] * isum * mk;
                }
            }
        }
    }
}

extern "C" void kernel_launch(void* const* d_in, const int* in_sizes, int n_in,
                              void* d_out, int out_size, void* d_ws, size_t ws_size,
                              hipStream_t stream) {
    const float* x      = (const float*)d_in[0];
    const float* coords = (const float*)d_in[1];
    const float* mask   = (const float*)d_in[2];
    const float* W1  = (const float*)d_in[3];
    const float* b1  = (const float*)d_in[4];
    const float* g1  = (const float*)d_in[5];
    const float* be1 = (const float*)d_in[6];
    const float* W2  = (const float*)d_in[7];
    const float* b2  = (const float*)d_in[8];
    const float* g2  = (const float*)d_in[9];
    const float* be2 = (const float*)d_in[10];
    const float* W3  = (const float*)d_in[11];
    const float* b3  = (const float*)d_in[12];
    const float* temp= (const float*)d_in[13];

    float* out        = (float*)d_out;
    float* out_plddt  = out;
    float* out_logits = out + (size_t)ROWS;
    float* out_probs  = out_logits + (size_t)ROWS * NB_;

    unsigned short* wt = (unsigned short*)d_ws;

    // A: setup || pLDDT (R13-verified arrangement)
    kernelA<<<SETUP_BLOCKS + PLDDT_BLOCKS, 512, 0, stream>>>(
        W1, W2, W3, wt, coords, mask, out_plddt);
    // B: in-wave MLP (consumes wt)
    mlp_inwave<<<MLP_BLOCKS, 512, 0, stream>>>(
        x, mask, b1, g1, be1, b2, g2, be2, b3, temp, wt, out_logits, out_probs);
}

// Round 19
// 23.846 us; speedup vs baseline: 1.9008x; 1.9008x over previous
//
#include <hip/hip_runtime.h>
#include <float.h>
#include <math.h>

#define B_   4
#define S_   2048
#define DIN_ 256
#define DH_  128
#define NB_  50
#define NBP_ 64
#define ROWS (B_ * S_)
#define MB   16      // rows per MLP block (R8-verified structure)

#define MLP_BLOCKS   (ROWS / MB)            // 512
#define SETUP_BLOCKS 14                     // 14 x 512 = 7168 slots
#define PLDDT_ROWSPB 32
#define PLDDT_BLOCKS (ROWS / PLDDT_ROWSPB)  // 256

typedef __attribute__((ext_vector_type(8))) short  short8;
typedef __attribute__((ext_vector_type(4))) float  f32x4;
typedef __attribute__((ext_vector_type(2))) float  f32x2;

__device__ __forceinline__ unsigned short bf16_rne(float f) {
    unsigned u = __builtin_bit_cast(unsigned, f);
    u = u + 0x7fffu + ((u >> 16) & 1u);
    return (unsigned short)(u >> 16);
}

// ---------------------------------------------------------------------------
// Kernel A: blocks [0,14) = weight setup (verified layout, unchanged math);
//           blocks [14, 14+256) = pLDDT (VALU-optimized, 32 rows/block).
// pLDDT never reads wt -> no intra-launch ordering hazard.
// ---------------------------------------------------------------------------
__global__ __launch_bounds__(512) void kernelA(
    const float* __restrict__ W1, const float* __restrict__ W2,
    const float* __restrict__ W3, unsigned short* __restrict__ wt,
    const float* __restrict__ coords, const float* __restrict__ mask,
    float* __restrict__ out_plddt)
{
    __shared__ f32x4 sP[S_];
    const int tid = threadIdx.x;

    if (blockIdx.x < SETUP_BLOCKS) {
        // ---- setup: weights -> MFMA-fragment-ordered bf16 ----
        const int t = blockIdx.x * 512 + tid;           // 0..7167
        const int l = t & 63, m = l & 15, kg = l >> 4;
        float src[8];
        int dst;
        if (t < 4096) {
            const int c = t >> 6, nt = c >> 3, ks = c & 7;
            const int n = nt * 16 + m, k = ks * 32 + kg * 8;
#pragma unroll
            for (int i = 0; i < 8; ++i) src[i] = W1[(k + i) * DH_ + n];
            dst = t * 8;
        } else if (t < 6144) {
            const int s = t - 4096, c = s >> 6, nt = c >> 2, ks = c & 3;
            const int n = nt * 16 + m, k = ks * 32 + kg * 8;
#pragma unroll
            for (int i = 0; i < 8; ++i) src[i] = W2[(k + i) * DH_ + n];
            dst = 32768 + s * 8;
        } else {
            const int s = t - 6144, c = s >> 6, nt = c >> 2, ks = c & 3;
            const int n = nt * 16 + m, k = ks * 32 + kg * 8;
#pragma unroll
            for (int i = 0; i < 8; ++i) src[i] = (n < NB_) ? W3[(k + i) * NB_ + n] : 0.f;
            dst = 49152 + s * 8;
        }
        union { short8 v; unsigned short u[8]; } H;
#pragma unroll
        for (int i = 0; i < 8; ++i) H.u[i] = bf16_rne(src[i]);
        *(short8*)&wt[dst] = H.v;
        return;
    }

    // ==================== pLDDT path ====================
    const int lane = tid & 63;
    const int w    = tid >> 6;
    const int pb   = blockIdx.x - SETUP_BLOCKS;      // 0..255
    const int row0 = pb * PLDDT_ROWSPB;
    const int b    = row0 >> 11;
    const int ib0  = row0 & (S_ - 1);

    const float* cb = coords + (size_t)b * S_ * 3;
    const float* mb = mask   + (size_t)b * S_;

    {   // stage all 2048 points: 4 per thread (x,y,z,mask)
        union { f32x4 v[3]; float f[12]; } C;
        const float* cp = cb + tid * 12;
#pragma unroll
        for (int q = 0; q < 3; ++q) C.v[q] = *(const f32x4*)(cp + q * 4);
        union { f32x4 v; float f[4]; } M;
        M.v = *(const f32x4*)(mb + tid * 4);
#pragma unroll
        for (int q = 0; q < 4; ++q)
            sP[tid * 4 + q] = (f32x4){C.f[q*3], C.f[q*3+1], C.f[q*3+2], M.f[q]};
    }
    __syncthreads();

    f32x4 PI[4];
#pragma unroll
    for (int ii = 0; ii < 4; ++ii) PI[ii] = sP[ib0 + w * 4 + ii];

    const f32x2 Px[2] = {{PI[0][0], PI[1][0]}, {PI[2][0], PI[3][0]}};
    const f32x2 Py[2] = {{PI[0][1], PI[1][1]}, {PI[2][1], PI[3][1]}};
    const f32x2 Pz[2] = {{PI[0][2], PI[1][2]}, {PI[2][2], PI[3][2]}};

    int cnt[4] = {0,0,0,0}, ws[4] = {0,0,0,0};
#pragma unroll 2
    for (int j = lane; j < S_; j += 64) {
        const f32x4 p = sP[j];
        // masked-out j -> d2 ~ 1e30 (all counts 0); the 1e-35 bias makes the
        // self-pair (d2==0) exponent trick exact and never perturbs compares.
        const float gd = (p[3] > 0.f) ? 1e-35f : 1e30f;
        const f32x2 pg = {gd, gd};
        const f32x2 px = {p[0], p[0]}, py = {p[1], p[1]}, pz = {p[2], p[2]};
#pragma unroll
        for (int pr = 0; pr < 2; ++pr) {
            f32x2 dx = Px[pr] - px;
            f32x2 dy = Py[pr] - py;
            f32x2 dz = Pz[pr] - pz;
            f32x2 d2 = __builtin_elementwise_fma(dx, dx,
                       __builtin_elementwise_fma(dy, dy,
                       __builtin_elementwise_fma(dz, dz, pg)));
#pragma unroll
            for (int el = 0; el < 2; ++el) {
                const int ii = pr * 2 + el;
                const float d2e = d2[el];
                cnt[ii] += (d2e <= 225.f);
                // thresholds d2 <= {0.25,1,4,16} = 4^k: count via exponent.
                const unsigned u = __builtin_bit_cast(unsigned, d2e);
                int c = (132 - (int)((u - 1u) >> 23)) >> 1;
                c = c < 0 ? 0 : (c > 4 ? 4 : c);
                ws[ii] += c;
            }
        }
    }
#pragma unroll
    for (int ii = 0; ii < 4; ++ii) {
        int acc = (cnt[ii] << 16) | ws[ii];   // ws<=8192, cnt<=2048 after reduce
        for (int off = 32; off; off >>= 1) acc += __shfl_xor(acc, off);
        if (lane == 0) {
            const int ct = acc >> 16, wv = acc & 0xFFFF;
            const float r = (ct > 0) ? (wv * 25.f / (float)ct) : 0.f;
            out_plddt[row0 + w * 4 + ii] = r * PI[ii][3];
        }
    }
}

// ---------------------------------------------------------------------------
// Kernel B: MLP only — R8-verified body (bf16 MFMA, 16 rows/block, 8 waves,
// n-split 16 cols; stats stride 20). 512 blocks -> good occupancy.
// ---------------------------------------------------------------------------
__global__ __launch_bounds__(512) void kernelB(
    const float* __restrict__ x, const float* __restrict__ mask,
    const float* __restrict__ b1, const float* __restrict__ g1, const float* __restrict__ be1,
    const float* __restrict__ b2, const float* __restrict__ g2, const float* __restrict__ be2,
    const float* __restrict__ b3, const float* __restrict__ temp,
    const unsigned short* __restrict__ wt,
    float* __restrict__ out_logits, float* __restrict__ out_probs)
{
    __shared__ unsigned short sA[MB * DIN_];
    __shared__ float sStats[MB][20];
    __shared__ float sL[MB * NBP_];

    const int tid  = threadIdx.x;
    const int lane = tid & 63;
    const int w    = tid >> 6;
    const int m    = lane & 15;
    const int kg   = lane >> 4;
    const int row0 = blockIdx.x * MB;

    // ---- stage x[16][256] as swizzled bf16 ----
    {
        const int r  = tid >> 5;
        const int kc = (tid & 31) << 3;
        const float* xp = x + (size_t)(row0 + r) * DIN_ + kc;
        f32x4 a = *(const f32x4*)xp;
        f32x4 b = *(const f32x4*)(xp + 4);
        union { short8 v; unsigned short u[8]; } H;
#pragma unroll
        for (int i = 0; i < 8; ++i)
            H.u[i] = bf16_rne((i < 4) ? a[i] : b[i - 4]);
        const int idx = (r * 256 + kc) ^ ((r & 7) << 3);
        *(short8*)&sA[idx] = H.v;
    }
    __syncthreads();

    const int n12 = w * 16 + m;

    // ---- stage 1 GEMM ----
    f32x4 aA = {0,0,0,0}, aB = {0,0,0,0};
    {
        const unsigned short* bp = wt + (w * 8) * 512;
#pragma unroll
        for (int ks = 0; ks < 8; ++ks) {
            const int ia = (m * 256 + ks * 32 + kg * 8) ^ ((m & 7) << 3);
            short8 ah = *(const short8*)&sA[ia];
            short8 bh = *(const short8*)&bp[ks * 512 + lane * 8];
            f32x4& ac = (ks & 1) ? aB : aA;
            ac = __builtin_amdgcn_mfma_f32_16x16x32_bf16(ah, bh, ac, 0, 0, 0);
        }
    }

    // ---- LN1 + relu -> h1 ----
    {
        const float bb = b1[n12], gg = g1[n12], ee = be1[n12];
        float v[4];
#pragma unroll
        for (int j = 0; j < 4; ++j) v[j] = aA[j] + aB[j] + bb;
#pragma unroll
        for (int j = 0; j < 4; ++j) {
            float sv = v[j], qv = v[j] * v[j];
            for (int off = 1; off < 16; off <<= 1) { sv += __shfl_xor(sv, off); qv += __shfl_xor(qv, off); }
            if (m == 0) { sStats[kg * 4 + j][w * 2] = sv; sStats[kg * 4 + j][w * 2 + 1] = qv; }
        }
        __syncthreads();
#pragma unroll
        for (int j = 0; j < 4; ++j) {
            const int r = kg * 4 + j;
            f32x4 s0 = *(const f32x4*)&sStats[r][0];
            f32x4 s1 = *(const f32x4*)&sStats[r][4];
            f32x4 s2 = *(const f32x4*)&sStats[r][8];
            f32x4 s3 = *(const f32x4*)&sStats[r][12];
            const float S = s0[0]+s0[2]+s1[0]+s1[2]+s2[0]+s2[2]+s3[0]+s3[2];
            const float Q = s0[1]+s0[3]+s1[1]+s1[3]+s2[1]+s2[3]+s3[1]+s3[3];
            const float mean = S * (1.f / DH_);
            const float inv  = rsqrtf(Q * (1.f / DH_) - mean * mean + 1e-5f);
            const float h = fmaxf(fmaf((v[j] - mean) * inv, gg, ee), 0.f);
            const int idx = (r * 128 + n12) ^ ((r & 7) << 3);
            sA[idx] = bf16_rne(h);
        }
    }
    __syncthreads();

    // ---- stage 2 GEMM ----
    aA = (f32x4){0,0,0,0}; aB = (f32x4){0,0,0,0};
    {
        const unsigned short* bp = wt + 32768 + (w * 4) * 512;
#pragma unroll
        for (int ks = 0; ks < 4; ++ks) {
            const int ia = (m * 128 + ks * 32 + kg * 8) ^ ((m & 7) << 3);
            short8 ah = *(const short8*)&sA[ia];
            short8 bh = *(const short8*)&bp[ks * 512 + lane * 8];
            f32x4& ac = (ks & 1) ? aB : aA;
            ac = __builtin_amdgcn_mfma_f32_16x16x32_bf16(ah, bh, ac, 0, 0, 0);
        }
    }

    // ---- LN2 + relu -> h2 ----
    {
        const float bb = b2[n12], gg = g2[n12], ee = be2[n12];
        float v[4];
#pragma unroll
        for (int j = 0; j < 4; ++j) v[j] = aA[j] + aB[j] + bb;
#pragma unroll
        for (int j = 0; j < 4; ++j) {
            float sv = v[j], qv = v[j] * v[j];
            for (int off = 1; off < 16; off <<= 1) { sv += __shfl_xor(sv, off); qv += __shfl_xor(qv, off); }
            if (m == 0) { sStats[kg * 4 + j][w * 2] = sv; sStats[kg * 4 + j][w * 2 + 1] = qv; }
        }
        __syncthreads();
#pragma unroll
        for (int j = 0; j < 4; ++j) {
            const int r = kg * 4 + j;
            f32x4 s0 = *(const f32x4*)&sStats[r][0];
            f32x4 s1 = *(const f32x4*)&sStats[r][4];
            f32x4 s2 = *(const f32x4*)&sStats[r][8];
            f32x4 s3 = *(const f32x4*)&sStats[r][12];
            const float S = s0[0]+s0[2]+s1[0]+s1[2]+s2[0]+s2[2]+s3[0]+s3[2];
            const float Q = s0[1]+s0[3]+s1[1]+s1[3]+s2[1]+s2[3]+s3[1]+s3[3];
            const float mean = S * (1.f / DH_);
            const float inv  = rsqrtf(Q * (1.f / DH_) - mean * mean + 1e-5f);
            const float h = fmaxf(fmaf((v[j] - mean) * inv, gg, ee), 0.f);
            const int idx = (r * 128 + n12) ^ ((r & 7) << 3);
            sA[idx] = bf16_rne(h);
        }
    }
    __syncthreads();

    // ---- stage 3 GEMM (waves 0..3) ----
    if (w < 4) {
        f32x4 cA = {0,0,0,0}, cB = {0,0,0,0};
        const unsigned short* bp = wt + 49152 + (w * 4) * 512;
#pragma unroll
        for (int ks = 0; ks < 4; ++ks) {
            const int ia = (m * 128 + ks * 32 + kg * 8) ^ ((m & 7) << 3);
            short8 ah = *(const short8*)&sA[ia];
            short8 bh = *(const short8*)&bp[ks * 512 + lane * 8];
            f32x4& ac = (ks & 1) ? cB : cA;
            ac = __builtin_amdgcn_mfma_f32_16x16x32_bf16(ah, bh, ac, 0, 0, 0);
        }
        const int n = w * 16 + m;
        const float bv = (n < NB_) ? b3[n] : 0.f;
        const float invT = 1.f / temp[0];
#pragma unroll
        for (int j = 0; j < 4; ++j)
            sL[(kg * 4 + j) * NBP_ + n] = (cA[j] + cB[j] + bv) * invT;
    }
    __syncthreads();

    // ---- softmax over 50 cols + masked stores ----
    if (tid < 256) {
        const int r  = tid >> 4;
        const int c0 = (tid & 15) * 4;
        f32x4 lg = *(const f32x4*)&sL[r * NBP_ + c0];
        float mx = -FLT_MAX;
#pragma unroll
        for (int i = 0; i < 4; ++i) if (c0 + i < NB_) mx = fmaxf(mx, lg[i]);
        for (int off = 1; off < 16; off <<= 1) mx = fmaxf(mx, __shfl_xor(mx, off));
        float e[4]; float sm = 0.f;
#pragma unroll
        for (int i = 0; i < 4; ++i) { e[i] = (c0 + i < NB_) ? expf(lg[i] - mx) : 0.f; sm += e[i]; }
        for (int off = 1; off < 16; off <<= 1) sm += __shfl_xor(sm, off);
        const float isum = 1.f / sm;
        const float mk = mask[row0 + r];
        float* ol = out_logits + (size_t)(row0 + r) * NB_;
        float* op = out_probs  + (size_t)(row0 + r) * NB_;
#pragma unroll
        for (int i = 0; i < 4; ++i) {
            const int c = c0 + i;
            if (c < NB_) { ol[c] = lg[i] * mk; op[c] = e[i] * isum * mk; }
        }
    }
}

extern "C" void kernel_launch(void* const* d_in, const int* in_sizes, int n_in,
                              void* d_out, int out_size, void* d_ws, size_t ws_size,
                              hipStream_t stream) {
    const float* x      = (const float*)d_in[0];
    const float* coords = (const float*)d_in[1];
    const float* mask   = (const float*)d_in[2];
    const float* W1  = (const float*)d_in[3];
    const float* b1  = (const float*)d_in[4];
    const float* g1  = (const float*)d_in[5];
    const float* be1 = (const float*)d_in[6];
    const float* W2  = (const float*)d_in[7];
    const float* b2  = (const float*)d_in[8];
    const float* g2  = (const float*)d_in[9];
    const float* be2 = (const float*)d_in[10];
    const float* W3  = (const float*)d_in[11];
    const float* b3  = (const float*)d_in[12];
    const float* temp= (const float*)d_in[13];

    float* out        = (float*)d_out;
    float* out_plddt  = out;
    float* out_logits = out + (size_t)ROWS;
    float* out_probs  = out_logits + (size_t)ROWS * NB_;

    unsigned short* wt = (unsigned short*)d_ws;

    // A: setup || pLDDT (pLDDT doesn't read wt; stream order protects B)
    kernelA<<<SETUP_BLOCKS + PLDDT_BLOCKS, 512, 0, stream>>>(
        W1, W2, W3, wt, coords, mask, out_plddt);
    // B: MLP (consumes wt)
    kernelB<<<MLP_BLOCKS, 512, 0, stream>>>(
        x, mask, b1, g1, be1, b2, g2, be2, b3, temp, wt, out_logits, out_probs);
}

// Round 20
// 23.765 us; speedup vs baseline: 1.9072x; 1.0034x over previous
//
#include <hip/hip_runtime.h>
#include <float.h>
#include <math.h>

#define B_   4
#define S_   2048
#define DIN_ 256
#define DH_  128
#define NB_  50
#define NBP_ 64
#define ROWS (B_ * S_)
#define MB   16      // rows per MLP block (R8-verified structure)

#define MLP_BLOCKS   (ROWS / MB)            // 512
#define SETUP_BLOCKS 14                     // 14 x 512 = 7168 slots
#define PLDDT_ROWSPB 32
#define PLDDT_BLOCKS (ROWS / PLDDT_ROWSPB)  // 256

typedef __attribute__((ext_vector_type(8))) short  short8;
typedef __attribute__((ext_vector_type(4))) float  f32x4;
typedef __attribute__((ext_vector_type(2))) float  f32x2;

__device__ __forceinline__ unsigned short bf16_rne(float f) {
    unsigned u = __builtin_bit_cast(unsigned, f);
    u = u + 0x7fffu + ((u >> 16) & 1u);
    return (unsigned short)(u >> 16);
}

// ---------------------------------------------------------------------------
// Kernel A: blocks [0,14) = weight setup; [14, 14+256) = pLDDT (32 rows/blk).
// pLDDT blocks additionally PREFETCH x into L2/L3 (mem pipes idle during the
// VALU loop) so kernelB's cold-replay staging hits cache instead of HBM.
// ---------------------------------------------------------------------------
__global__ __launch_bounds__(512) void kernelA(
    const float* __restrict__ W1, const float* __restrict__ W2,
    const float* __restrict__ W3, unsigned short* __restrict__ wt,
    const float* __restrict__ coords, const float* __restrict__ mask,
    const float* __restrict__ x,
    float* __restrict__ out_plddt)
{
    __shared__ f32x4 sP[S_];
    const int tid = threadIdx.x;

    if (blockIdx.x < SETUP_BLOCKS) {
        // ---- setup: weights -> MFMA-fragment-ordered bf16 ----
        const int t = blockIdx.x * 512 + tid;           // 0..7167
        const int l = t & 63, m = l & 15, kg = l >> 4;
        float src[8];
        int dst;
        if (t < 4096) {
            const int c = t >> 6, nt = c >> 3, ks = c & 7;
            const int n = nt * 16 + m, k = ks * 32 + kg * 8;
#pragma unroll
            for (int i = 0; i < 8; ++i) src[i] = W1[(k + i) * DH_ + n];
            dst = t * 8;
        } else if (t < 6144) {
            const int s = t - 4096, c = s >> 6, nt = c >> 2, ks = c & 3;
            const int n = nt * 16 + m, k = ks * 32 + kg * 8;
#pragma unroll
            for (int i = 0; i < 8; ++i) src[i] = W2[(k + i) * DH_ + n];
            dst = 32768 + s * 8;
        } else {
            const int s = t - 6144, c = s >> 6, nt = c >> 2, ks = c & 3;
            const int n = nt * 16 + m, k = ks * 32 + kg * 8;
#pragma unroll
            for (int i = 0; i < 8; ++i) src[i] = (n < NB_) ? W3[(k + i) * NB_ + n] : 0.f;
            dst = 49152 + s * 8;
        }
        union { short8 v; unsigned short u[8]; } H;
#pragma unroll
        for (int i = 0; i < 8; ++i) H.u[i] = bf16_rne(src[i]);
        *(short8*)&wt[dst] = H.v;
        return;
    }

    // ==================== pLDDT path ====================
    const int lane = tid & 63;
    const int w    = tid >> 6;
    const int pb   = blockIdx.x - SETUP_BLOCKS;      // 0..255
    const int row0 = pb * PLDDT_ROWSPB;
    const int b    = row0 >> 11;
    const int ib0  = row0 & (S_ - 1);

    const float* cb = coords + (size_t)b * S_ * 3;
    const float* mb = mask   + (size_t)b * S_;

    {   // stage all 2048 points: 4 per thread (x,y,z,mask)
        union { f32x4 v[3]; float f[12]; } C;
        const float* cp = cb + tid * 12;
#pragma unroll
        for (int q = 0; q < 3; ++q) C.v[q] = *(const f32x4*)(cp + q * 4);
        union { f32x4 v; float f[4]; } M;
        M.v = *(const f32x4*)(mb + tid * 4);
#pragma unroll
        for (int q = 0; q < 4; ++q)
            sP[tid * 4 + q] = (f32x4){C.f[q*3], C.f[q*3+1], C.f[q*3+2], M.f[q]};
    }
    __syncthreads();

    // ---- issue x prefetch (32 KB/block; 256 blocks = full 8 MB of x).
    // Loads complete into L2/L3 while the VALU loop below runs; consumed
    // only by the keep-alive asm at the end (no stall, no DCE).
    f32x4 pf0, pf1, pf2, pf3;
    {
        const f32x4* xpf = (const f32x4*)x + (size_t)pb * 2048 + tid * 4;
        pf0 = xpf[0]; pf1 = xpf[1]; pf2 = xpf[2]; pf3 = xpf[3];
    }

    f32x4 PI[4];
#pragma unroll
    for (int ii = 0; ii < 4; ++ii) PI[ii] = sP[ib0 + w * 4 + ii];

    const f32x2 Px[2] = {{PI[0][0], PI[1][0]}, {PI[2][0], PI[3][0]}};
    const f32x2 Py[2] = {{PI[0][1], PI[1][1]}, {PI[2][1], PI[3][1]}};
    const f32x2 Pz[2] = {{PI[0][2], PI[1][2]}, {PI[2][2], PI[3][2]}};

    int cnt[4] = {0,0,0,0}, ws[4] = {0,0,0,0};
#pragma unroll 2
    for (int j = lane; j < S_; j += 64) {
        const f32x4 p = sP[j];
        // masked-out j -> d2 ~ 1e30 (all counts 0); the 1e-35 bias makes the
        // self-pair (d2==0) exponent trick exact and never perturbs compares.
        const float gd = (p[3] > 0.f) ? 1e-35f : 1e30f;
        const f32x2 pg = {gd, gd};
        const f32x2 px = {p[0], p[0]}, py = {p[1], p[1]}, pz = {p[2], p[2]};
#pragma unroll
        for (int pr = 0; pr < 2; ++pr) {
            f32x2 dx = Px[pr] - px;
            f32x2 dy = Py[pr] - py;
            f32x2 dz = Pz[pr] - pz;
            f32x2 d2 = __builtin_elementwise_fma(dx, dx,
                       __builtin_elementwise_fma(dy, dy,
                       __builtin_elementwise_fma(dz, dz, pg)));
#pragma unroll
            for (int el = 0; el < 2; ++el) {
                const int ii = pr * 2 + el;
                const float d2e = d2[el];
                cnt[ii] += (d2e <= 225.f);
                // thresholds d2 <= {0.25,1,4,16} = 4^k: count via exponent.
                const unsigned u = __builtin_bit_cast(unsigned, d2e);
                int c = (132 - (int)((u - 1u) >> 23)) >> 1;
                c = c < 0 ? 0 : (c > 4 ? 4 : c);
                ws[ii] += c;
            }
        }
    }
#pragma unroll
    for (int ii = 0; ii < 4; ++ii) {
        int acc = (cnt[ii] << 16) | ws[ii];   // ws<=8192, cnt<=2048 after reduce
        for (int off = 32; off; off >>= 1) acc += __shfl_xor(acc, off);
        if (lane == 0) {
            const int ct = acc >> 16, wv = acc & 0xFFFF;
            const float r = (ct > 0) ? (wv * 25.f / (float)ct) : 0.f;
            out_plddt[row0 + w * 4 + ii] = r * PI[ii][3];
        }
    }

    // keep prefetch loads live (rule #17) — placed last so the implicit
    // waitcnt lands after all useful work.
    asm volatile("" :: "v"(pf0[0]), "v"(pf0[1]), "v"(pf0[2]), "v"(pf0[3]),
                       "v"(pf1[0]), "v"(pf1[1]), "v"(pf1[2]), "v"(pf1[3]),
                       "v"(pf2[0]), "v"(pf2[1]), "v"(pf2[2]), "v"(pf2[3]),
                       "v"(pf3[0]), "v"(pf3[1]), "v"(pf3[2]), "v"(pf3[3]));
}

// ---------------------------------------------------------------------------
// Kernel B: MLP only — R8-verified body (bf16 MFMA, 16 rows/block, 8 waves,
// n-split 16 cols; stats stride 20). 512 blocks -> good occupancy.
// ---------------------------------------------------------------------------
__global__ __launch_bounds__(512) void kernelB(
    const float* __restrict__ x, const float* __restrict__ mask,
    const float* __restrict__ b1, const float* __restrict__ g1, const float* __restrict__ be1,
    const float* __restrict__ b2, const float* __restrict__ g2, const float* __restrict__ be2,
    const float* __restrict__ b3, const float* __restrict__ temp,
    const unsigned short* __restrict__ wt,
    float* __restrict__ out_logits, float* __restrict__ out_probs)
{
    __shared__ unsigned short sA[MB * DIN_];
    __shared__ float sStats[MB][20];
    __shared__ float sL[MB * NBP_];

    const int tid  = threadIdx.x;
    const int lane = tid & 63;
    const int w    = tid >> 6;
    const int m    = lane & 15;
    const int kg   = lane >> 4;
    const int row0 = blockIdx.x * MB;

    // ---- stage x[16][256] as swizzled bf16 ----
    {
        const int r  = tid >> 5;
        const int kc = (tid & 31) << 3;
        const float* xp = x + (size_t)(row0 + r) * DIN_ + kc;
        f32x4 a = *(const f32x4*)xp;
        f32x4 b = *(const f32x4*)(xp + 4);
        union { short8 v; unsigned short u[8]; } H;
#pragma unroll
        for (int i = 0; i < 8; ++i)
            H.u[i] = bf16_rne((i < 4) ? a[i] : b[i - 4]);
        const int idx = (r * 256 + kc) ^ ((r & 7) << 3);
        *(short8*)&sA[idx] = H.v;
    }
    __syncthreads();

    const int n12 = w * 16 + m;

    // ---- stage 1 GEMM ----
    f32x4 aA = {0,0,0,0}, aB = {0,0,0,0};
    {
        const unsigned short* bp = wt + (w * 8) * 512;
#pragma unroll
        for (int ks = 0; ks < 8; ++ks) {
            const int ia = (m * 256 + ks * 32 + kg * 8) ^ ((m & 7) << 3);
            short8 ah = *(const short8*)&sA[ia];
            short8 bh = *(const short8*)&bp[ks * 512 + lane * 8];
            f32x4& ac = (ks & 1) ? aB : aA;
            ac = __builtin_amdgcn_mfma_f32_16x16x32_bf16(ah, bh, ac, 0, 0, 0);
        }
    }

    // ---- LN1 + relu -> h1 ----
    {
        const float bb = b1[n12], gg = g1[n12], ee = be1[n12];
        float v[4];
#pragma unroll
        for (int j = 0; j < 4; ++j) v[j] = aA[j] + aB[j] + bb;
#pragma unroll
        for (int j = 0; j < 4; ++j) {
            float sv = v[j], qv = v[j] * v[j];
            for (int off = 1; off < 16; off <<= 1) { sv += __shfl_xor(sv, off); qv += __shfl_xor(qv, off); }
            if (m == 0) { sStats[kg * 4 + j][w * 2] = sv; sStats[kg * 4 + j][w * 2 + 1] = qv; }
        }
        __syncthreads();
#pragma unroll
        for (int j = 0; j < 4; ++j) {
            const int r = kg * 4 + j;
            f32x4 s0 = *(const f32x4*)&sStats[r][0];
            f32x4 s1 = *(const f32x4*)&sStats[r][4];
            f32x4 s2 = *(const f32x4*)&sStats[r][8];
            f32x4 s3 = *(const f32x4*)&sStats[r][12];
            const float S = s0[0]+s0[2]+s1[0]+s1[2]+s2[0]+s2[2]+s3[0]+s3[2];
            const float Q = s0[1]+s0[3]+s1[1]+s1[3]+s2[1]+s2[3]+s3[1]+s3[3];
            const float mean = S * (1.f / DH_);
            const float inv  = rsqrtf(Q * (1.f / DH_) - mean * mean + 1e-5f);
            const float h = fmaxf(fmaf((v[j] - mean) * inv, gg, ee), 0.f);
            const int idx = (r * 128 + n12) ^ ((r & 7) << 3);
            sA[idx] = bf16_rne(h);
        }
    }
    __syncthreads();

    // ---- stage 2 GEMM ----
    aA = (f32x4){0,0,0,0}; aB = (f32x4){0,0,0,0};
    {
        const unsigned short* bp = wt + 32768 + (w * 4) * 512;
#pragma unroll
        for (int ks = 0; ks < 4; ++ks) {
            const int ia = (m * 128 + ks * 32 + kg * 8) ^ ((m & 7) << 3);
            short8 ah = *(const short8*)&sA[ia];
            short8 bh = *(const short8*)&bp[ks * 512 + lane * 8];
            f32x4& ac = (ks & 1) ? aB : aA;
            ac = __builtin_amdgcn_mfma_f32_16x16x32_bf16(ah, bh, ac, 0, 0, 0);
        }
    }

    // ---- LN2 + relu -> h2 ----
    {
        const float bb = b2[n12], gg = g2[n12], ee = be2[n12];
        float v[4];
#pragma unroll
        for (int j = 0; j < 4; ++j) v[j] = aA[j] + aB[j] + bb;
#pragma unroll
        for (int j = 0; j < 4; ++j) {
            float sv = v[j], qv = v[j] * v[j];
            for (int off = 1; off < 16; off <<= 1) { sv += __shfl_xor(sv, off); qv += __shfl_xor(qv, off); }
            if (m == 0) { sStats[kg * 4 + j][w * 2] = sv; sStats[kg * 4 + j][w * 2 + 1] = qv; }
        }
        __syncthreads();
#pragma unroll
        for (int j = 0; j < 4; ++j) {
            const int r = kg * 4 + j;
            f32x4 s0 = *(const f32x4*)&sStats[r][0];
            f32x4 s1 = *(const f32x4*)&sStats[r][4];
            f32x4 s2 = *(const f32x4*)&sStats[r][8];
            f32x4 s3 = *(const f32x4*)&sStats[r][12];
            const float S = s0[0]+s0[2]+s1[0]+s1[2]+s2[0]+s2[2]+s3[0]+s3[2];
            const float Q = s0[1]+s0[3]+s1[1]+s1[3]+s2[1]+s2[3]+s3[1]+s3[3];
            const float mean = S * (1.f / DH_);
            const float inv  = rsqrtf(Q * (1.f / DH_) - mean * mean + 1e-5f);
            const float h = fmaxf(fmaf((v[j] - mean) * inv, gg, ee), 0.f);
            const int idx = (r * 128 + n12) ^ ((r & 7) << 3);
            sA[idx] = bf16_rne(h);
        }
    }
    __syncthreads();

    // ---- stage 3 GEMM (waves 0..3) ----
    if (w < 4) {
        f32x4 cA = {0,0,0,0}, cB = {0,0,0,0};
        const unsigned short* bp = wt + 49152 + (w * 4) * 512;
#pragma unroll
        for (int ks = 0; ks < 4; ++ks) {
            const int ia = (m * 128 + ks * 32 + kg * 8) ^ ((m & 7) << 3);
            short8 ah = *(const short8*)&sA[ia];
            short8 bh = *(const short8*)&bp[ks * 512 + lane * 8];
            f32x4& ac = (ks & 1) ? cB : cA;
            ac = __builtin_amdgcn_mfma_f32_16x16x32_bf16(ah, bh, ac, 0, 0, 0);
        }
        const int n = w * 16 + m;
        const float bv = (n < NB_) ? b3[n] : 0.f;
        const float invT = 1.f / temp[0];
#pragma unroll
        for (int j = 0; j < 4; ++j)
            sL[(kg * 4 + j) * NBP_ + n] = (cA[j] + cB[j] + bv) * invT;
    }
    __syncthreads();

    // ---- softmax over 50 cols + masked stores ----
    if (tid < 256) {
        const int r  = tid >> 4;
        const int c0 = (tid & 15) * 4;
        f32x4 lg = *(const f32x4*)&sL[r * NBP_ + c0];
        float mx = -FLT_MAX;
#pragma unroll
        for (int i = 0; i < 4; ++i) if (c0 + i < NB_) mx = fmaxf(mx, lg[i]);
        for (int off = 1; off < 16; off <<= 1) mx = fmaxf(mx, __shfl_xor(mx, off));
        float e[4]; float sm = 0.f;
#pragma unroll
        for (int i = 0; i < 4; ++i) { e[i] = (c0 + i < NB_) ? expf(lg[i] - mx) : 0.f; sm += e[i]; }
        for (int off = 1; off < 16; off <<= 1) sm += __shfl_xor(sm, off);
        const float isum = 1.f / sm;
        const float mk = mask[row0 + r];
        float* ol = out_logits + (size_t)(row0 + r) * NB_;
        float* op = out_probs  + (size_t)(row0 + r) * NB_;
#pragma unroll
        for (int i = 0; i < 4; ++i) {
            const int c = c0 + i;
            if (c < NB_) { ol[c] = lg[i] * mk; op[c] = e[i] * isum * mk; }
        }
    }
}

extern "C" void kernel_launch(void* const* d_in, const int* in_sizes, int n_in,
                              void* d_out, int out_size, void* d_ws, size_t ws_size,
                              hipStream_t stream) {
    const float* x      = (const float*)d_in[0];
    const float* coords = (const float*)d_in[1];
    const float* mask   = (const float*)d_in[2];
    const float* W1  = (const float*)d_in[3];
    const float* b1  = (const float*)d_in[4];
    const float* g1  = (const float*)d_in[5];
    const float* be1 = (const float*)d_in[6];
    const float* W2  = (const float*)d_in[7];
    const float* b2  = (const float*)d_in[8];
    const float* g2  = (const float*)d_in[9];
    const float* be2 = (const float*)d_in[10];
    const float* W3  = (const float*)d_in[11];
    const float* b3  = (const float*)d_in[12];
    const float* temp= (const float*)d_in[13];

    float* out        = (float*)d_out;
    float* out_plddt  = out;
    float* out_logits = out + (size_t)ROWS;
    float* out_probs  = out_logits + (size_t)ROWS * NB_;

    unsigned short* wt = (unsigned short*)d_ws;

    // A: setup || pLDDT (+ x prefetch into L2/L3 for B's cold start)
    kernelA<<<SETUP_BLOCKS + PLDDT_BLOCKS, 512, 0, stream>>>(
        W1, W2, W3, wt, coords, mask, x, out_plddt);
    // B: MLP (consumes wt; x now cache-warm)
    kernelB<<<MLP_BLOCKS, 512, 0, stream>>>(
        x, mask, b1, g1, be1, b2, g2, be2, b3, temp, wt, out_logits, out_probs);
}